// Round 4
// baseline (872.242 us; speedup 1.0000x reference)
//
#include <hip/hip_runtime.h>

#define D 64
#define D4 (D / 4)        // 16 float4 per row
#define NPART 8           // blockIdx%8 ~ XCD (speed heuristic only)
#define BSHIFT 7          // 128 nodes per bucket
#define BROWS 128
#define NB_MAX 1024       // supports n_nodes <= 131072
#define ROWSTRIDE 68      // 64 + 4 pad floats: spreads ds_add_f32 banks
#define HG 512            // blocks in hist/append passes (must match!)

__device__ __forceinline__ float elu1(float z) {
    return z > 0.0f ? z : expm1f(z);
}

// ---------- K1: emb = elu(x*w); zero the (p-major) bucket counters ----------
__global__ void emb_zero_counts_kernel(const float* __restrict__ x,
                                       const float* __restrict__ w,
                                       float* __restrict__ emb,
                                       int* __restrict__ counts,
                                       int total4, int ncnt) {
    int i = blockIdx.x * blockDim.x + threadIdx.x;
    if (i < ncnt) counts[i] = 0;
    if (i >= total4) return;
    float4 xv = ((const float4*)x)[i];
    float4 wv = ((const float4*)w)[i & (D4 - 1)];
    float4 r;
    r.x = elu1(xv.x * wv.x);
    r.y = elu1(xv.y * wv.y);
    r.z = elu1(xv.z * wv.z);
    r.w = elu1(xv.w * wv.w);
    ((float4*)emb)[i] = r;
}

// ---------- K2: histogram of dst>>BSHIFT, LDS-local then p-major flush ----------
__global__ void hist_kernel(const int* __restrict__ dst,
                            int* __restrict__ counts,   // [NPART][NB]
                            int n_edges, int NB) {
    __shared__ int lh[NB_MAX];
    int tid = threadIdx.x;
    int p = blockIdx.x & (NPART - 1);
    for (int b = tid; b < NB; b += blockDim.x) lh[b] = 0;
    __syncthreads();
    for (int e = blockIdx.x * blockDim.x + tid; e < n_edges; e += HG * blockDim.x)
        atomicAdd(&lh[dst[e] >> BSHIFT], 1);
    __syncthreads();
    for (int b = tid; b < NB; b += blockDim.x) {
        int v = lh[b];
        if (v) atomicAdd(&counts[p * NB + b], v);
    }
}

// ---------- K3: single-block scan over b-major enumeration of counts ----------
// offsets (b-major, size NB*8+1); cursor (p-major) primed with start positions.
__global__ void scan_kernel(const int* __restrict__ counts,  // [NPART][NB]
                            int* __restrict__ offsets,       // [NB*8+1] b-major
                            int* __restrict__ cursor,        // [NPART][NB]
                            int NB) {
    __shared__ int wsum[16];
    const int NBP = NB * NPART;
    int tid = threadIdx.x;           // 1024 threads
    int lane = tid & 63, wid = tid >> 6;
    int v[8]; int s = 0;
    #pragma unroll
    for (int j = 0; j < 8; j++) {
        int idx = tid * 8 + j;
        int val = 0;
        if (idx < NBP) { int b = idx >> 3, p = idx & 7; val = counts[p * NB + b]; }
        v[j] = val; s += val;
    }
    int incl = s;
    #pragma unroll
    for (int off = 1; off < 64; off <<= 1) {
        int t = __shfl_up(incl, off, 64);
        if (lane >= off) incl += t;
    }
    if (lane == 63) wsum[wid] = incl;
    __syncthreads();
    if (tid == 0) {
        int r = 0;
        for (int k = 0; k < 16; k++) { int t = wsum[k]; wsum[k] = r; r += t; }
    }
    __syncthreads();
    int run = wsum[wid] + (incl - s);
    #pragma unroll
    for (int j = 0; j < 8; j++) {
        int idx = tid * 8 + j;
        if (idx < NBP) {
            int b = idx >> 3, p = idx & 7;
            offsets[idx] = run;
            cursor[p * NB + b] = run;
        }
        run += v[j];
    }
    if (tid == 1023) offsets[NBP] = run;
}

// ---------- K4: append edges at (p,b) cursor tips; packed (dlocal<<18)|src ----
__global__ void append_kernel(const int* __restrict__ src,
                              const int* __restrict__ dst,
                              int* __restrict__ cursor,     // [NPART][NB]
                              int* __restrict__ sorted,     // [n_edges]
                              int n_edges, int NB) {
    int tid = threadIdx.x;
    int p = blockIdx.x & (NPART - 1);
    for (int e = blockIdx.x * blockDim.x + tid; e < n_edges; e += HG * blockDim.x) {
        int d = dst[e];
        int b = d >> BSHIFT;
        int pos = atomicAdd(&cursor[p * NB + b], 1);
        sorted[pos] = ((d & (BROWS - 1)) << 18) | src[e];
    }
}

// ---------- K5: one block per bucket; LDS row accumulation ----------
__global__ void accum_kernel(const float* __restrict__ emb,
                             const int* __restrict__ sorted,
                             const int* __restrict__ offsets,  // b-major
                             float* __restrict__ out, int n_nodes) {
    __shared__ float acc[BROWS * ROWSTRIDE];   // 34,816 B
    const int b = blockIdx.x;
    const int tid = threadIdx.x;               // 256
    // zero LDS (float4)
    for (int i = tid; i < BROWS * (ROWSTRIDE / 4); i += 256)
        ((float4*)acc)[i] = make_float4(0.f, 0.f, 0.f, 0.f);
    __syncthreads();

    const int beg = offsets[b * 8];
    const int end = offsets[b * 8 + 8];
    const int grp = tid >> 4;                  // 16 groups of 16 lanes
    const int c   = tid & 15;
    const float4* emb4 = (const float4*)emb;

    int e = beg + grp;
    for (; e + 16 < end; e += 32) {
        int pk0 = sorted[e];
        int pk1 = sorted[e + 16];
        float4 v0 = emb4[(pk0 & 0x3FFFF) * D4 + c];
        float4 v1 = emb4[(pk1 & 0x3FFFF) * D4 + c];
        float* a0 = &acc[(pk0 >> 18) * ROWSTRIDE + c * 4];
        float* a1 = &acc[(pk1 >> 18) * ROWSTRIDE + c * 4];
        atomicAdd(a0 + 0, v0.x); atomicAdd(a0 + 1, v0.y);
        atomicAdd(a0 + 2, v0.z); atomicAdd(a0 + 3, v0.w);
        atomicAdd(a1 + 0, v1.x); atomicAdd(a1 + 1, v1.y);
        atomicAdd(a1 + 2, v1.z); atomicAdd(a1 + 3, v1.w);
    }
    if (e < end) {
        int pk = sorted[e];
        float4 v = emb4[(pk & 0x3FFFF) * D4 + c];
        float* a = &acc[(pk >> 18) * ROWSTRIDE + c * 4];
        atomicAdd(a + 0, v.x); atomicAdd(a + 1, v.y);
        atomicAdd(a + 2, v.z); atomicAdd(a + 3, v.w);
    }
    __syncthreads();

    // write out: rows [b*128, ...) clipped to n_nodes
    const int lo = b << BSHIFT;
    const int rows_here = min(BROWS, n_nodes - lo);
    float4* out4 = (float4*)out;
    for (int i = tid; i < rows_here * D4; i += 256) {
        int row = i >> 4, cc = i & 15;
        out4[(lo + row) * D4 + cc] = *(const float4*)&acc[row * ROWSTRIDE + cc * 4];
    }
}

// ---------- Fallback: atomic scatter ----------
__global__ void zero_out_kernel(float* __restrict__ out, int total4) {
    int i = blockIdx.x * blockDim.x + threadIdx.x;
    if (i < total4) ((float4*)out)[i] = make_float4(0.f, 0.f, 0.f, 0.f);
}

__global__ void scatter_fused_kernel(const float* __restrict__ x,
                                     const float* __restrict__ w,
                                     const int* __restrict__ src,
                                     const int* __restrict__ dst,
                                     float* __restrict__ out, int n_edges) {
    int t = blockIdx.x * blockDim.x + threadIdx.x;
    int e = t >> 4;
    int c = t & 15;
    if (e >= n_edges) return;
    int s = src[e];
    int d = dst[e];
    float4 xv = ((const float4*)x)[s * D4 + c];
    float4 wv = ((const float4*)w)[c];
    float* o = out + d * D + c * 4;
    unsafeAtomicAdd(o + 0, elu1(xv.x * wv.x));
    unsafeAtomicAdd(o + 1, elu1(xv.y * wv.y));
    unsafeAtomicAdd(o + 2, elu1(xv.z * wv.z));
    unsafeAtomicAdd(o + 3, elu1(xv.w * wv.w));
}

extern "C" void kernel_launch(void* const* d_in, const int* in_sizes, int n_in,
                              void* d_out, int out_size, void* d_ws, size_t ws_size,
                              hipStream_t stream) {
    const float* x   = (const float*)d_in[0];   // [N, 64] fp32
    const float* w   = (const float*)d_in[1];   // [1, 64] fp32
    const int*   src = (const int*)d_in[2];     // [E] int32
    const int*   dst = (const int*)d_in[3];     // [E] int32
    float* out = (float*)d_out;

    const int n_nodes = in_sizes[0] / D;
    const int n_edges = in_sizes[2];
    const int total4  = n_nodes * D4;
    const int block = 256;

    const int NB = (n_nodes + BROWS - 1) >> BSHIFT;
    auto align16 = [](size_t v) { return (v + 15) & ~size_t(15); };
    const size_t emb_b     = align16((size_t)n_nodes * D * sizeof(float));
    const size_t sorted_b  = align16((size_t)n_edges * sizeof(int));
    const size_t counts_b  = align16((size_t)NB * NPART * sizeof(int));
    const size_t cursor_b  = counts_b;
    const size_t offsets_b = align16(((size_t)NB * NPART + 1) * sizeof(int));
    const size_t need = emb_b + sorted_b + counts_b + cursor_b + offsets_b;

    if (ws_size >= need && NB <= NB_MAX && n_nodes <= (1 << 18)) {
        char* p = (char*)d_ws;
        float* emb     = (float*)p;  p += emb_b;
        int*   sorted  = (int*)p;    p += sorted_b;
        int*   counts  = (int*)p;    p += counts_b;
        int*   cursor  = (int*)p;    p += cursor_b;
        int*   offsets = (int*)p;

        emb_zero_counts_kernel<<<(total4 + block - 1) / block, block, 0, stream>>>(
            x, w, emb, counts, total4, NB * NPART);
        hist_kernel<<<HG, block, 0, stream>>>(dst, counts, n_edges, NB);
        scan_kernel<<<1, 1024, 0, stream>>>(counts, offsets, cursor, NB);
        append_kernel<<<HG, block, 0, stream>>>(src, dst, cursor, sorted,
                                                n_edges, NB);
        accum_kernel<<<NB, block, 0, stream>>>(emb, sorted, offsets, out, n_nodes);
    } else {
        zero_out_kernel<<<(total4 + block - 1) / block, block, 0, stream>>>(out, total4);
        const int nt = n_edges * 16;
        scatter_fused_kernel<<<(nt + block - 1) / block, block, 0, stream>>>(
            x, w, src, dst, out, n_edges);
    }
}

// Round 5
// 241.968 us; speedup vs baseline: 3.6048x; 3.6048x over previous
//
#include <hip/hip_runtime.h>

#define D 64
#define D4 (D / 4)        // 16 float4 per row (fp32)
#define NPART 8           // blockIdx%8 ~ XCD (speed heuristic only)
#define BSHIFT 7          // 128 nodes per bucket
#define BROWS 128
#define NB_MAX 1024       // supports n_nodes <= 131072
#define HG 512            // blocks in hist/append passes (MUST match between them)

__device__ __forceinline__ float elu1(float z) {
    return z > 0.0f ? z : expm1f(z);
}

// pack two fp32 -> bf16 pair (RNE), elem a in low 16, b in high 16
__device__ __forceinline__ unsigned int bfpair(float a, float b) {
    unsigned int ua = __float_as_uint(a);
    unsigned int ub = __float_as_uint(b);
    ua = (ua + 0x7FFFu + ((ua >> 16) & 1u)) >> 16;
    ub = (ub + 0x7FFFu + ((ub >> 16) & 1u)) & 0xFFFF0000u;
    return ub | ua;
}

// ---------- K1: emb16 = bf16(elu(x*w)); zero (p-major) bucket counters ----------
__global__ void emb_zero_counts_kernel(const float* __restrict__ x,
                                       const float* __restrict__ w,
                                       unsigned int* __restrict__ emb16, // [N*32] uint = 2 bf16
                                       int* __restrict__ counts,
                                       int total4, int ncnt) {
    int i = blockIdx.x * blockDim.x + threadIdx.x;
    if (i < ncnt) counts[i] = 0;
    if (i >= total4) return;
    float4 xv = ((const float4*)x)[i];
    float4 wv = ((const float4*)w)[i & (D4 - 1)];
    float4 r;
    r.x = elu1(xv.x * wv.x);
    r.y = elu1(xv.y * wv.y);
    r.z = elu1(xv.z * wv.z);
    r.w = elu1(xv.w * wv.w);
    uint2 o;
    o.x = bfpair(r.x, r.y);
    o.y = bfpair(r.z, r.w);
    ((uint2*)emb16)[i] = o;
}

// ---------- K2: bucket histogram (per-block LDS, p-major flush) ----------
// Block q reads slice {e : (e/256) % HG == q}; flushes into partition p=q%8.
__global__ void hist_kernel(const int* __restrict__ dst,
                            int* __restrict__ counts,   // [NPART][NB]
                            int n_edges, int NB) {
    __shared__ int lh[NB_MAX];
    int tid = threadIdx.x;
    int p = blockIdx.x & (NPART - 1);
    for (int b = tid; b < NB; b += blockDim.x) lh[b] = 0;
    __syncthreads();
    for (int e = blockIdx.x * blockDim.x + tid; e < n_edges; e += HG * blockDim.x)
        atomicAdd(&lh[dst[e] >> BSHIFT], 1);
    __syncthreads();
    for (int b = tid; b < NB; b += blockDim.x) {
        int v = lh[b];
        if (v) atomicAdd(&counts[p * NB + b], v);
    }
}

// ---------- K3: single-block scan over b-major (bucket,partition) counts ----------
__global__ void scan_kernel(const int* __restrict__ counts,  // [NPART][NB]
                            int* __restrict__ offsets,       // [NB*8+1] b-major
                            int* __restrict__ cursor,        // [NPART][NB]
                            int NB) {
    __shared__ int wsum[16];
    const int NBP = NB * NPART;
    int tid = threadIdx.x;           // 1024 threads
    int lane = tid & 63, wid = tid >> 6;
    int v[8]; int s = 0;
    #pragma unroll
    for (int j = 0; j < 8; j++) {
        int idx = tid * 8 + j;
        int val = 0;
        if (idx < NBP) { int b = idx >> 3, p = idx & 7; val = counts[p * NB + b]; }
        v[j] = val; s += val;
    }
    int incl = s;
    #pragma unroll
    for (int off = 1; off < 64; off <<= 1) {
        int t = __shfl_up(incl, off, 64);
        if (lane >= off) incl += t;
    }
    if (lane == 63) wsum[wid] = incl;
    __syncthreads();
    if (tid == 0) {
        int r = 0;
        for (int k = 0; k < 16; k++) { int t = wsum[k]; wsum[k] = r; r += t; }
    }
    __syncthreads();
    int run = wsum[wid] + (incl - s);
    #pragma unroll
    for (int j = 0; j < 8; j++) {
        int idx = tid * 8 + j;
        if (idx < NBP) {
            int b = idx >> 3, p = idx & 7;
            offsets[idx] = run;
            cursor[p * NB + b] = run;
        }
        run += v[j];
    }
    if (tid == 1023) offsets[NBP] = run;
}

// ---------- K4: append edges at (p,bucket) tips; packed (dlocal<<18)|src ----------
__global__ void append_kernel(const int* __restrict__ src,
                              const int* __restrict__ dst,
                              int* __restrict__ cursor,     // [NPART][NB]
                              int* __restrict__ sorted,
                              int n_edges, int NB) {
    int tid = threadIdx.x;
    int p = blockIdx.x & (NPART - 1);
    for (int e = blockIdx.x * blockDim.x + tid; e < n_edges; e += HG * blockDim.x) {
        int d = dst[e];
        int b = d >> BSHIFT;
        int pos = atomicAdd(&cursor[p * NB + b], 1);
        sorted[pos] = ((d & (BROWS - 1)) << 18) | src[e];
    }
}

// ---------- K4b: fine counting-sort within each bucket; emit node offsets ----------
// Block b: sorts its bucket's edges into full dst order (src only) in an
// 8KB L2-resident window; LDS atomics here are trivial in count.
__global__ void fine_sort_kernel(const int* __restrict__ sorted,
                                 const int* __restrict__ offsets,  // b-major
                                 int* __restrict__ sorted2,
                                 int* __restrict__ node_off,       // [n_nodes+1]
                                 int n_nodes, int NB) {
    __shared__ int rcount[BROWS];
    __shared__ int rcur[BROWS];
    const int b = blockIdx.x;
    const int tid = threadIdx.x;       // 256
    const int beg = offsets[b * 8];
    const int end = offsets[b * 8 + 8];
    if (tid < BROWS) rcount[tid] = 0;
    __syncthreads();
    for (int i = beg + tid; i < end; i += 256)
        atomicAdd(&rcount[(unsigned)sorted[i] >> 18], 1);
    __syncthreads();
    if (tid == 0) {
        int run = beg;
        for (int r = 0; r < BROWS; r++) { rcur[r] = run; run += rcount[r]; }
    }
    __syncthreads();
    const int lo = b << BSHIFT;
    if (tid < BROWS && lo + tid < n_nodes) node_off[lo + tid] = rcur[tid];
    if (b == NB - 1 && tid == 0) node_off[n_nodes] = end;
    __syncthreads();
    for (int i = beg + tid; i < end; i += 256) {
        int pk = sorted[i];
        int pos = atomicAdd(&rcur[(unsigned)pk >> 18], 1);
        sorted2[pos] = pk & 0x3FFFF;
    }
}

// ---------- K5: wave per node; 8 groups x 8 lanes; bf16 rows; register accum ----------
__global__ void gather_sum_kernel(const unsigned int* __restrict__ emb16,
                                  const int* __restrict__ sorted2,
                                  const int* __restrict__ node_off,
                                  float* __restrict__ out, int n_nodes) {
    int wave = (blockIdx.x * blockDim.x + threadIdx.x) >> 6;
    if (wave >= n_nodes) return;
    const int lane = threadIdx.x & 63;
    const int g = lane >> 3;          // 8 edge slots
    const int c = lane & 7;           // 8 int4-chunks per 128B row
    const int beg = node_off[wave], end = node_off[wave + 1];
    const int4* row = (const int4*)emb16;   // 8 int4 per row

    float acc[8] = {0.f, 0.f, 0.f, 0.f, 0.f, 0.f, 0.f, 0.f};
    int e = beg + g;
    for (; e + 8 < end; e += 16) {
        int s0 = sorted2[e];
        int s1 = sorted2[e + 8];
        int4 u0 = row[s0 * 8 + c];
        int4 u1 = row[s1 * 8 + c];
        acc[0] += __uint_as_float((unsigned)u0.x << 16) + __uint_as_float((unsigned)u1.x << 16);
        acc[1] += __uint_as_float(u0.x & 0xFFFF0000u)   + __uint_as_float(u1.x & 0xFFFF0000u);
        acc[2] += __uint_as_float((unsigned)u0.y << 16) + __uint_as_float((unsigned)u1.y << 16);
        acc[3] += __uint_as_float(u0.y & 0xFFFF0000u)   + __uint_as_float(u1.y & 0xFFFF0000u);
        acc[4] += __uint_as_float((unsigned)u0.z << 16) + __uint_as_float((unsigned)u1.z << 16);
        acc[5] += __uint_as_float(u0.z & 0xFFFF0000u)   + __uint_as_float(u1.z & 0xFFFF0000u);
        acc[6] += __uint_as_float((unsigned)u0.w << 16) + __uint_as_float((unsigned)u1.w << 16);
        acc[7] += __uint_as_float(u0.w & 0xFFFF0000u)   + __uint_as_float(u1.w & 0xFFFF0000u);
    }
    if (e < end) {
        int s0 = sorted2[e];
        int4 u0 = row[s0 * 8 + c];
        acc[0] += __uint_as_float((unsigned)u0.x << 16);
        acc[1] += __uint_as_float(u0.x & 0xFFFF0000u);
        acc[2] += __uint_as_float((unsigned)u0.y << 16);
        acc[3] += __uint_as_float(u0.y & 0xFFFF0000u);
        acc[4] += __uint_as_float((unsigned)u0.z << 16);
        acc[5] += __uint_as_float(u0.z & 0xFFFF0000u);
        acc[6] += __uint_as_float((unsigned)u0.w << 16);
        acc[7] += __uint_as_float(u0.w & 0xFFFF0000u);
    }
    #pragma unroll
    for (int off = 8; off <= 32; off <<= 1) {
        #pragma unroll
        for (int k = 0; k < 8; k++) acc[k] += __shfl_xor(acc[k], off, 64);
    }
    if (g == 0) {
        float4* out4 = (float4*)out;
        out4[wave * D4 + c * 2]     = make_float4(acc[0], acc[1], acc[2], acc[3]);
        out4[wave * D4 + c * 2 + 1] = make_float4(acc[4], acc[5], acc[6], acc[7]);
    }
}

// ---------- Fallback: atomic scatter ----------
__global__ void zero_out_kernel(float* __restrict__ out, int total4) {
    int i = blockIdx.x * blockDim.x + threadIdx.x;
    if (i < total4) ((float4*)out)[i] = make_float4(0.f, 0.f, 0.f, 0.f);
}

__global__ void scatter_fused_kernel(const float* __restrict__ x,
                                     const float* __restrict__ w,
                                     const int* __restrict__ src,
                                     const int* __restrict__ dst,
                                     float* __restrict__ out, int n_edges) {
    int t = blockIdx.x * blockDim.x + threadIdx.x;
    int e = t >> 4;
    int c = t & 15;
    if (e >= n_edges) return;
    int s = src[e];
    int d = dst[e];
    float4 xv = ((const float4*)x)[s * D4 + c];
    float4 wv = ((const float4*)w)[c];
    float* o = out + d * D + c * 4;
    unsafeAtomicAdd(o + 0, elu1(xv.x * wv.x));
    unsafeAtomicAdd(o + 1, elu1(xv.y * wv.y));
    unsafeAtomicAdd(o + 2, elu1(xv.z * wv.z));
    unsafeAtomicAdd(o + 3, elu1(xv.w * wv.w));
}

extern "C" void kernel_launch(void* const* d_in, const int* in_sizes, int n_in,
                              void* d_out, int out_size, void* d_ws, size_t ws_size,
                              hipStream_t stream) {
    const float* x   = (const float*)d_in[0];   // [N, 64] fp32
    const float* w   = (const float*)d_in[1];   // [1, 64] fp32
    const int*   src = (const int*)d_in[2];     // [E] int32
    const int*   dst = (const int*)d_in[3];     // [E] int32
    float* out = (float*)d_out;

    const int n_nodes = in_sizes[0] / D;
    const int n_edges = in_sizes[2];
    const int total4  = n_nodes * D4;
    const int block = 256;

    const int NB = (n_nodes + BROWS - 1) >> BSHIFT;
    auto align16 = [](size_t v) { return (v + 15) & ~size_t(15); };
    const size_t emb_b     = align16((size_t)n_nodes * D * 2);           // bf16
    const size_t sorted_b  = align16((size_t)n_edges * sizeof(int));
    const size_t sorted2_b = sorted_b;
    const size_t counts_b  = align16((size_t)NB * NPART * sizeof(int));
    const size_t cursor_b  = counts_b;
    const size_t offsets_b = align16(((size_t)NB * NPART + 1) * sizeof(int));
    const size_t nodeoff_b = align16((size_t)(n_nodes + 1) * sizeof(int));
    const size_t need = emb_b + sorted_b + sorted2_b + counts_b + cursor_b +
                        offsets_b + nodeoff_b;

    if (ws_size >= need && NB <= NB_MAX && n_nodes <= (1 << 18)) {
        char* p = (char*)d_ws;
        unsigned int* emb16 = (unsigned int*)p;  p += emb_b;
        int* sorted   = (int*)p;  p += sorted_b;
        int* sorted2  = (int*)p;  p += sorted2_b;
        int* counts   = (int*)p;  p += counts_b;
        int* cursor   = (int*)p;  p += cursor_b;
        int* offsets  = (int*)p;  p += offsets_b;
        int* node_off = (int*)p;

        emb_zero_counts_kernel<<<(total4 + block - 1) / block, block, 0, stream>>>(
            x, w, emb16, counts, total4, NB * NPART);
        hist_kernel<<<HG, block, 0, stream>>>(dst, counts, n_edges, NB);
        scan_kernel<<<1, 1024, 0, stream>>>(counts, offsets, cursor, NB);
        append_kernel<<<HG, block, 0, stream>>>(src, dst, cursor, sorted,
                                                n_edges, NB);
        fine_sort_kernel<<<NB, block, 0, stream>>>(sorted, offsets, sorted2,
                                                   node_off, n_nodes, NB);
        const int wave_blocks = (n_nodes * 64 + block - 1) / block;
        gather_sum_kernel<<<wave_blocks, block, 0, stream>>>(
            emb16, sorted2, node_off, out, n_nodes);
    } else {
        zero_out_kernel<<<(total4 + block - 1) / block, block, 0, stream>>>(out, total4);
        const int nt = n_edges * 16;
        scatter_fused_kernel<<<(nt + block - 1) / block, block, 0, stream>>>(
            x, w, src, dst, out, n_edges);
    }
}